// Round 13
// baseline (412.679 us; speedup 1.0000x reference)
//
#include <hip/hip_runtime.h>
#include <math.h>

#define BB 16384
#define HH 512

typedef short short8 __attribute__((ext_vector_type(8)));
typedef float f32x4 __attribute__((ext_vector_type(4)));
typedef unsigned short ushort_t;

__device__ __forceinline__ float sigm(float v){ return 1.0f/(1.0f+expf(-v)); }

__device__ __forceinline__ unsigned short f2bf(float f){
    unsigned int u = __float_as_uint(f);
    u = u + 0x7FFFu + ((u>>16)&1u);
    return (unsigned short)(u>>16);
}
__device__ __forceinline__ float bf2f(unsigned short h){
    return __uint_as_float(((unsigned int)h)<<16);
}
__device__ __forceinline__ void gll16(const void* g, void* l){
    __builtin_amdgcn_global_load_lds((const __attribute__((address_space(1))) void*)g,
                                     (__attribute__((address_space(3))) void*)l, 16, 0, 0);
}
__device__ __forceinline__ void split_store(float v, ushort_t* ph, ushort_t* pl, int j){
    unsigned short h = f2bf(v);
    unsigned short l = f2bf(v - bf2f(h));
    ph[j] = h; pl[j] = l;
}

// ---------------- merged prepass (r10 verbatim) ----------------
__global__ void k_prep_all(
    const float* __restrict__ x, const float* __restrict__ h0, const float* __restrict__ c0,
    const float* __restrict__ W_ih, const float* __restrict__ W_hh,
    const float* __restrict__ b_ih, const float* __restrict__ b_hh,
    const float* __restrict__ W_sp, const float* __restrict__ W_sc, const float* __restrict__ W_tp,
    const float* __restrict__ b_sp, const float* __restrict__ b_sc, const float* __restrict__ b_tp,
    ushort_t* __restrict__ A1h, ushort_t* __restrict__ A1l,
    ushort_t* __restrict__ A2h, ushort_t* __restrict__ A2l,
    ushort_t* __restrict__ B1h, ushort_t* __restrict__ B1l,
    ushort_t* __restrict__ B2h, ushort_t* __restrict__ B2l,
    float* __restrict__ bgp, float* __restrict__ bs2)
{
    int bid = blockIdx.x;
    if (bid < 8192) {
        int u = bid*256 + threadIdx.x;
        int r  = u & 255;
        int c  = (u >> 8) & 3;
        int kt = (u >> 10) & 31;
        int tm = u >> 15;
        int row = tm*256 + r;
        int k0 = kt*32 + c*8;
        const float* src = (k0 < 512) ? (x + (size_t)row*512 + k0)
                                      : (h0 + (size_t)row*512 + (k0-512));
        float4 v0 = *(const float4*)(src);
        float4 v1 = *(const float4*)(src+4);
        float vv[8] = {v0.x,v0.y,v0.z,v0.w,v1.x,v1.y,v1.z,v1.w};
        size_t off = (size_t)u * 8;
#pragma unroll
        for (int j=0;j<8;++j) split_store(vv[j], A1h+off, A1l+off, j);
    } else if (bid < 12288) {
        int u = (bid-8192)*256 + threadIdx.x;
        int r  = u & 127;
        int c  = (u >> 7) & 3;
        int tk = (u >> 9) & 15;
        int tm = u >> 13;
        int row = tm*128 + r;
        int k0 = tk*32 + c*8;
        const float* src = c0 + (size_t)row*512 + k0;
        float4 v0 = *(const float4*)(src);
        float4 v1 = *(const float4*)(src+4);
        float vv[8] = {v0.x,v0.y,v0.z,v0.w,v1.x,v1.y,v1.z,v1.w};
        size_t off = ((size_t)tm*32 + tk)*4096 + (size_t)(c*128 + r)*8;
#pragma unroll
        for (int j=0;j<8;++j) split_store(vv[j], A2h+off, A2l+off, j);
    } else if (bid < 13312) {
        int u = (bid-12288)*256 + threadIdx.x;
        int r  = u & 255;
        int c  = (u >> 8) & 3;
        int kt = (u >> 10) & 31;
        int tn = u >> 15;
        int g = (r>>4)&3;
        int h = tn*64 + (r>>6)*16 + (r&15);
        int wrow = g*512 + h;
        int k0 = kt*32 + c*8;
        const float* src = (k0 < 512) ? (W_ih + (size_t)wrow*512 + k0)
                                      : (W_hh + (size_t)wrow*512 + (k0-512));
        float4 v0 = *(const float4*)(src);
        float4 v1 = *(const float4*)(src+4);
        float vv[8] = {v0.x,v0.y,v0.z,v0.w,v1.x,v1.y,v1.z,v1.w};
        size_t off = (size_t)u * 8;
#pragma unroll
        for (int j=0;j<8;++j) split_store(vv[j], B1h+off, B1l+off, j);
        if (kt == 0 && c == 0) bgp[tn*256 + r] = b_ih[wrow] + b_hh[wrow];
    } else {
        int u = (bid-13312)*256 + threadIdx.x;
        int r  = u & 127;
        int c  = (u >> 7) & 3;
        int tk = (u >> 9) & 31;
        int tn = u >> 14;
        int n = tn*128 + r;
        int k0 = tk*32 + c*8;
        float vv[8];
        if (n < 256) {
            const float* src = (k0 < 512) ? (W_sp + (size_t)n*512 + k0)
                                          : (W_sc + (size_t)n*512 + (k0-512));
            float4 v0 = *(const float4*)(src);
            float4 v1 = *(const float4*)(src+4);
            vv[0]=v0.x; vv[1]=v0.y; vv[2]=v0.z; vv[3]=v0.w;
            vv[4]=v1.x; vv[5]=v1.y; vv[6]=v1.z; vv[7]=v1.w;
        } else if (k0 < 512) {
            const float* src = W_tp + (size_t)(n-256)*512 + k0;
            float4 v0 = *(const float4*)(src);
            float4 v1 = *(const float4*)(src+4);
            vv[0]=v0.x; vv[1]=v0.y; vv[2]=v0.z; vv[3]=v0.w;
            vv[4]=v1.x; vv[5]=v1.y; vv[6]=v1.z; vv[7]=v1.w;
        } else {
#pragma unroll
            for (int j=0;j<8;++j) vv[j] = 0.0f;
        }
        size_t off = (size_t)u * 8;
#pragma unroll
        for (int j=0;j<8;++j) split_store(vv[j], B2h+off, B2l+off, j);
        if (tk == 0 && c == 0) bs2[n] = (n < 256) ? (b_sp[n] + b_sc[n]) : b_tp[n-256];
    }
}

// ---------- GEMM1: gates, 256x256, 4 FAT waves (128x128 each), K''=3072 ----------
// 2x2 wave grid halves LDS read amplification (96KB -> 64KB per step).
// Step T: read frags T+1 (16 ds_read), stage T+3 (8 gll16), 64 MFMA on regs T.
#define GSTEP(T, CA, CB, NA, NB, DO_READS, DO_STAGE, VMASM)                          \
  {                                                                                  \
    if (DO_READS) {                                                                  \
        const ushort_t* bufA1 = &lds[((T)+1) & 3][0];                                \
        const ushort_t* bufB1 = &lds[((T)+1) & 3][8192];                             \
        _Pragma("unroll") for (int f = 0; f < 8; ++f)                                \
            NA[f] = *(const short8*)&bufA1[aoff[f]];                                 \
        _Pragma("unroll") for (int f = 0; f < 8; ++f)                                \
            NB[f] = *(const short8*)&bufB1[boff[f]];                                 \
    }                                                                                \
    if (DO_STAGE) {                                                                  \
        const int uu = (T) + 3;                                                      \
        const ushort_t* As_ = ((uu >> 5) == 1) ? Al : Ah;                            \
        const ushort_t* Bs_ = ((uu >> 5) == 2) ? Bl : Bh;                            \
        const ushort_t* gA = As_ + ((size_t)tm*32 + (uu & 31))*8192;                 \
        const ushort_t* gB = Bs_ + ((size_t)tn*32 + (uu & 31))*8192;                 \
        ushort_t* dA = &lds[uu & 3][0];                                              \
        ushort_t* dB = &lds[uu & 3][8192];                                           \
        _Pragma("unroll") for (int q = 0; q < 4; ++q)                                \
            gll16(gA + q*2048 + (size_t)tid*8, dA + q*2048 + tid*8);                 \
        _Pragma("unroll") for (int q = 0; q < 4; ++q)                                \
            gll16(gB + q*2048 + (size_t)tid*8, dB + q*2048 + tid*8);                 \
    }                                                                                \
    _Pragma("unroll") for (int fm = 0; fm < 8; ++fm)                                 \
        _Pragma("unroll") for (int fn = 0; fn < 8; ++fn)                             \
            acc[fm][fn] = __builtin_amdgcn_mfma_f32_16x16x32_bf16(CA[fm], CB[fn], acc[fm][fn], 0,0,0); \
    VMASM;                                                                           \
    asm volatile("s_barrier" ::: "memory");                                          \
  }

__global__ __launch_bounds__(256, 1) void k_gemm_gates(
    const ushort_t* __restrict__ Ah, const ushort_t* __restrict__ Al,
    const ushort_t* __restrict__ Bh, const ushort_t* __restrict__ Bl,
    const float* __restrict__ bgp, const float* __restrict__ c0,
    float* __restrict__ outH, float* __restrict__ outC,
    ushort_t* __restrict__ A2h, ushort_t* __restrict__ A2l)
{
    __shared__ __align__(16) ushort_t lds[4][16384];   // 128 KiB
    const int tid  = threadIdx.x;
    const int lane = tid & 63;
    const int wid  = tid >> 6;
    const int wr   = wid >> 1;        // 0..1 -> rows wr*128
    const int wc   = wid & 1;         // 0..1 -> cols wc*128
    const int l15  = lane & 15;
    const int lq   = lane >> 4;
    const int bid  = (int)blockIdx.x;
    const int v    = (bid & 7)*64 + (bid >> 3);   // XCD swizzle
    const int tm   = v >> 3;          // 0..63
    const int tn   = v & 7;           // 0..7

    f32x4 acc[8][8];
#pragma unroll
    for (int fn = 0; fn < 8; ++fn) {
        float bv = bgp[tn*256 + wc*128 + fn*16 + l15];
#pragma unroll
        for (int fm = 0; fm < 8; ++fm) {
            acc[fm][fn][0]=bv; acc[fm][fn][1]=bv; acc[fm][fn][2]=bv; acc[fm][fn][3]=bv;
        }
    }

    int aoff[8], boff[8];
#pragma unroll
    for (int f = 0; f < 8; ++f) {
        aoff[f] = (lq*256 + wr*128 + f*16 + l15) * 8;
        boff[f] = (lq*256 + wc*128 + f*16 + l15) * 8;
    }

    short8 a0[8], b0[8], a1[8], b1[8];

    // prologue: stage steps 0,1,2 (24 loads); drain 0,1; read step-0 frags
#pragma unroll
    for (int u0 = 0; u0 < 3; ++u0) {
        const ushort_t* gA = Ah + ((size_t)tm*32 + u0)*8192;
        const ushort_t* gB = Bh + ((size_t)tn*32 + u0)*8192;
#pragma unroll
        for (int q = 0; q < 4; ++q)
            gll16(gA + q*2048 + (size_t)tid*8, &lds[u0][q*2048 + tid*8]);
#pragma unroll
        for (int q = 0; q < 4; ++q)
            gll16(gB + q*2048 + (size_t)tid*8, &lds[u0][8192 + q*2048 + tid*8]);
    }
    asm volatile("s_waitcnt vmcnt(8)" ::: "memory");
    asm volatile("s_barrier" ::: "memory");
#pragma unroll
    for (int f = 0; f < 8; ++f) a0[f] = *(const short8*)&lds[0][aoff[f]];
#pragma unroll
    for (int f = 0; f < 8; ++f) b0[f] = *(const short8*)&lds[0][8192 + boff[f]];

    for (int t = 0; t < 92; t += 2) {
        GSTEP(t,   a0, b0, a1, b1, 1, 1, asm volatile("s_waitcnt vmcnt(8)" ::: "memory"));
        GSTEP(t+1, a1, b1, a0, b0, 1, 1, asm volatile("s_waitcnt vmcnt(8)" ::: "memory"));
    }
    GSTEP(92, a0, b0, a1, b1, 1, 1, asm volatile("s_waitcnt vmcnt(8)" ::: "memory"));
    GSTEP(93, a1, b1, a0, b0, 1, 0, asm volatile("s_waitcnt vmcnt(0)" ::: "memory"));
    GSTEP(94, a0, b0, a1, b1, 1, 0, ((void)0));
    GSTEP(95, a1, b1, a0, b0, 0, 0, ((void)0));

    // epilogue: gate g = fn&3, h-slot = wc*2 + (fn>>2)
#pragma unroll
    for (int fm = 0; fm < 8; ++fm) {
        int row0 = tm*256 + wr*128 + fm*16 + lq*4;
#pragma unroll
        for (int hg = 0; hg < 2; ++hg) {
            int h = tn*64 + (wc*2 + hg)*16 + l15;
#pragma unroll
            for (int r = 0; r < 4; ++r) {
                int row = row0 + r;
                size_t idx = (size_t)row*512 + h;
                float ig = sigm(acc[fm][hg*4+0][r]);
                float fg = sigm(acc[fm][hg*4+1][r]);
                float gg = tanhf(acc[fm][hg*4+2][r]);
                float og = sigm(acc[fm][hg*4+3][r]);
                float c1 = fg*c0[idx] + ig*gg;
                float h1 = og*tanhf(c1);
                outC[idx] = c1;
                outH[idx] = h1;
                unsigned short ch = f2bf(c1);
                unsigned short cl = f2bf(c1 - bf2f(ch));
                size_t a2 = ((size_t)(row>>7)*32 + 16 + (h>>5))*4096
                          + (size_t)((((h>>3)&3))*128 + (row&127))*8 + (h&7);
                A2h[a2] = ch;
                A2l[a2] = cl;
            }
        }
    }
}

// ---------- GEMM2: sg|tg, 128x128, K''=3072, ping-pong (r10 verbatim) ----------
#define SSTEP(T, CA, CB, NA, NB, DO_READS, DO_STAGE, VMASM)                          \
  {                                                                                  \
    if (DO_READS) {                                                                  \
        const ushort_t* bufA1 = &lds2[((T)+1) & 3][0];                               \
        const ushort_t* bufB1 = &lds2[((T)+1) & 3][4096];                            \
        _Pragma("unroll") for (int f = 0; f < 4; ++f)                                \
            NA[f] = *(const short8*)&bufA1[aoff[f]];                                 \
        _Pragma("unroll") for (int f = 0; f < 4; ++f)                                \
            NB[f] = *(const short8*)&bufB1[boff[f]];                                 \
    }                                                                                \
    if (DO_STAGE) {                                                                  \
        const int uu = (T) + 3;                                                      \
        const ushort_t* As_ = ((uu >> 5) == 1) ? Al : Ah;                            \
        const ushort_t* Bs_ = ((uu >> 5) == 2) ? Bl : Bh;                            \
        size_t ga = ((size_t)tm*32 + (uu & 31))*4096 + (size_t)tid*8;                \
        size_t gb = ((size_t)tn*32 + (uu & 31))*4096 + (size_t)tid*8;                \
        ushort_t* dA = &lds2[uu & 3][0];                                             \
        ushort_t* dB = &lds2[uu & 3][4096];                                          \
        gll16(As_ + ga,        dA + tid*8);                                          \
        gll16(As_ + ga + 2048, dA + 2048 + tid*8);                                   \
        gll16(Bs_ + gb,        dB + tid*8);                                          \
        gll16(Bs_ + gb + 2048, dB + 2048 + tid*8);                                   \
    }                                                                                \
    _Pragma("unroll") for (int fm = 0; fm < 4; ++fm)                                 \
        _Pragma("unroll") for (int fn = 0; fn < 4; ++fn)                             \
            acc[fm][fn] = __builtin_amdgcn_mfma_f32_16x16x32_bf16(CA[fm], CB[fn], acc[fm][fn], 0,0,0); \
    VMASM;                                                                           \
    asm volatile("s_barrier" ::: "memory");                                          \
  }

__global__ __launch_bounds__(256, 2) void k_gemm_sgtg(
    const ushort_t* __restrict__ Ah, const ushort_t* __restrict__ Al,
    const ushort_t* __restrict__ Bh, const ushort_t* __restrict__ Bl,
    const float* __restrict__ bs2,
    float* __restrict__ sgtg)
{
    __shared__ __align__(16) ushort_t lds2[4][8192];   // 64 KiB -> 2 blocks/CU
    const int tid  = threadIdx.x;
    const int lane = tid & 63;
    const int wid  = tid >> 6;
    const int wr   = wid >> 1;
    const int wc   = wid & 1;
    const int l15  = lane & 15;
    const int lq   = lane >> 4;
    const int bid  = (int)blockIdx.x;
    const int v    = (bid & 7)*64 + (bid >> 3);
    const int tm   = v >> 2;          // 0..127
    const int tn   = v & 3;           // 0..3

    f32x4 acc[4][4];
#pragma unroll
    for (int fn = 0; fn < 4; ++fn) {
        float bv = bs2[tn*128 + wc*64 + fn*16 + l15];
#pragma unroll
        for (int fm = 0; fm < 4; ++fm) {
            acc[fm][fn][0]=bv; acc[fm][fn][1]=bv; acc[fm][fn][2]=bv; acc[fm][fn][3]=bv;
        }
    }

    int aoff[4], boff[4];
#pragma unroll
    for (int f = 0; f < 4; ++f) {
        aoff[f] = (lq*128 + wr*64 + f*16 + l15) * 8;
        boff[f] = (lq*128 + wc*64 + f*16 + l15) * 8;
    }

    short8 a0[4], b0[4], a1[4], b1[4];

#pragma unroll
    for (int u0 = 0; u0 < 3; ++u0) {
        size_t ga = ((size_t)tm*32 + u0)*4096 + (size_t)tid*8;
        size_t gb = ((size_t)tn*32 + u0)*4096 + (size_t)tid*8;
        gll16(Ah + ga,        &lds2[u0][0]    + tid*8);
        gll16(Ah + ga + 2048, &lds2[u0][2048] + tid*8);
        gll16(Bh + gb,        &lds2[u0][4096] + tid*8);
        gll16(Bh + gb + 2048, &lds2[u0][6144] + tid*8);
    }
    asm volatile("s_waitcnt vmcnt(4)" ::: "memory");
    asm volatile("s_barrier" ::: "memory");
#pragma unroll
    for (int f = 0; f < 4; ++f) a0[f] = *(const short8*)&lds2[0][aoff[f]];
#pragma unroll
    for (int f = 0; f < 4; ++f) b0[f] = *(const short8*)&lds2[0][4096 + boff[f]];

    for (int t = 0; t < 92; t += 2) {
        SSTEP(t,   a0, b0, a1, b1, 1, 1, asm volatile("s_waitcnt vmcnt(4)" ::: "memory"));
        SSTEP(t+1, a1, b1, a0, b0, 1, 1, asm volatile("s_waitcnt vmcnt(4)" ::: "memory"));
    }
    SSTEP(92, a0, b0, a1, b1, 1, 1, asm volatile("s_waitcnt vmcnt(4)" ::: "memory"));
    SSTEP(93, a1, b1, a0, b0, 1, 0, asm volatile("s_waitcnt vmcnt(0)" ::: "memory"));
    SSTEP(94, a0, b0, a1, b1, 1, 0, ((void)0));
    SSTEP(95, a1, b1, a0, b0, 0, 0, ((void)0));

#pragma unroll
    for (int fm = 0; fm < 4; ++fm) {
        int row0 = tm*128 + wr*64 + fm*16 + lq*4;
#pragma unroll
        for (int fn = 0; fn < 4; ++fn) {
            int n = tn*128 + wc*64 + fn*16 + l15;
#pragma unroll
            for (int r = 0; r < 4; ++r) {
                int row = row0 + r;
                float vv = acc[fm][fn][r];
                vv = vv > 0.f ? vv : 0.01f*vv;
                sgtg[(size_t)row*512 + n] = vv;
            }
        }
    }
}

// ---------- final: row dots, threshold decision, gated writeback (r10 verbatim) ----------
__global__ __launch_bounds__(256) void k_final(
    const float* __restrict__ sgtg,
    const float* __restrict__ h0, const float* __restrict__ c0,
    const float* __restrict__ cum,
    const float* __restrict__ W_so, const float* __restrict__ b_so,
    const float* __restrict__ W_to, const float* __restrict__ b_to,
    float* __restrict__ outH, float* __restrict__ outC,
    float* __restrict__ outCum, float* __restrict__ outDelta, float* __restrict__ outProb)
{
    int w = threadIdx.x >> 6;
    int lane = threadIdx.x & 63;
    int b = blockIdx.x * 4 + w;
    const float* row = sgtg + (size_t)b * 512;
    float so = 0.f, to = 0.f;
#pragma unroll
    for (int u = 0; u < 4; ++u) {
        int c = lane + 64 * u;
        so = fmaf(row[c], W_so[c], so);
        to = fmaf(row[256 + c], W_to[c], to);
    }
#pragma unroll
    for (int off = 32; off; off >>= 1) {
        so += __shfl_down(so, off);
        to += __shfl_down(to, off);
    }
    so = __shfl(so, 0);
    to = __shfl(to, 0);
    float delta = sigm(so + b_so[0]);
    float thr   = sigm(to + b_to[0]);
    float cu = cum[b];
    float prob = cu + fminf(delta, 1.0f - cu);
    float hard = (prob > thr) ? 1.0f : 0.0f;
    if (lane == 0) {
        outDelta[b] = delta;
        outProb[b]  = prob;
        outCum[b]   = (1.0f - hard) * prob;
    }
    if (hard == 0.0f) {
#pragma unroll
        for (int u = 0; u < 8; ++u) {
            size_t idx = (size_t)b * 512 + lane + 64 * u;
            outH[idx] = h0[idx];
            outC[idx] = c0[idx];
        }
    }
}

extern "C" void kernel_launch(void* const* d_in, const int* in_sizes, int n_in,
                              void* d_out, int out_size, void* d_ws, size_t ws_size,
                              hipStream_t stream)
{
    const float* x    = (const float*)d_in[0];
    const float* h0   = (const float*)d_in[1];
    const float* c0   = (const float*)d_in[2];
    const float* cum  = (const float*)d_in[3];
    const float* W_ih = (const float*)d_in[4];
    const float* W_hh = (const float*)d_in[5];
    const float* b_ih = (const float*)d_in[6];
    const float* b_hh = (const float*)d_in[7];
    const float* W_sp = (const float*)d_in[8];
    const float* b_sp = (const float*)d_in[9];
    const float* W_sc = (const float*)d_in[10];
    const float* b_sc = (const float*)d_in[11];
    const float* W_so = (const float*)d_in[12];
    const float* b_so = (const float*)d_in[13];
    const float* W_tp = (const float*)d_in[14];
    const float* b_tp = (const float*)d_in[15];
    const float* W_to = (const float*)d_in[16];
    const float* b_to = (const float*)d_in[17];

    float* out      = (float*)d_out;
    float* outH     = out;
    float* outC     = out + (size_t)BB * HH;
    float* outCum   = out + (size_t)2 * BB * HH;
    float* outDelta = outCum + BB;
    float* outProb  = outDelta + BB;

    char* w = (char*)d_ws;
    ushort_t* A1h = (ushort_t*)(w);                       // 33,554,432 B
    ushort_t* A1l = (ushort_t*)(w + 33554432ull);         // 33,554,432 B
    ushort_t* A2h = (ushort_t*)(w + 67108864ull);         // 33,554,432 B
    ushort_t* A2l = (ushort_t*)(w + 100663296ull);        // 33,554,432 B
    ushort_t* B1h = (ushort_t*)(w + 134217728ull);        //  4,194,304 B
    ushort_t* B1l = (ushort_t*)(w + 138412032ull);        //  4,194,304 B
    ushort_t* B2h = (ushort_t*)(w + 142606336ull);        //  1,048,576 B
    ushort_t* B2l = (ushort_t*)(w + 143654912ull);        //  1,048,576 B
    float*    bgp = (float*)(w + 144703488ull);           //      8,192 B
    float*    bs2 = (float*)(w + 144711680ull);           //      2,048 B
    float*    sgtg = (float*)A1h;   // alias: A1 dead after k_gemm_gates

    k_prep_all<<<13568, 256, 0, stream>>>(x, h0, c0, W_ih, W_hh, b_ih, b_hh,
                                          W_sp, W_sc, W_tp, b_sp, b_sc, b_tp,
                                          A1h, A1l, A2h, A2l, B1h, B1l, B2h, B2l,
                                          bgp, bs2);
    k_gemm_gates<<<512, 256, 0, stream>>>(A1h, A1l, B1h, B1l, bgp, c0,
                                          outH, outC, A2h, A2l);
    k_gemm_sgtg<<<512, 256, 0, stream>>>(A2h, A2l, B2h, B2l, bs2, sgtg);
    k_final<<<4096, 256, 0, stream>>>(sgtg, h0, c0, cum, W_so, b_so, W_to, b_to,
                                      outH, outC, outCum, outDelta, outProb);
}

// Round 14
// 332.109 us; speedup vs baseline: 1.2426x; 1.2426x over previous
//
#include <hip/hip_runtime.h>
#include <math.h>

#define BB 16384
#define HH 512

typedef short short8 __attribute__((ext_vector_type(8)));
typedef float f32x4 __attribute__((ext_vector_type(4)));
typedef unsigned short ushort_t;

__device__ __forceinline__ float sigm(float v){ return 1.0f/(1.0f+expf(-v)); }

__device__ __forceinline__ unsigned short f2bf(float f){
    unsigned int u = __float_as_uint(f);
    u = u + 0x7FFFu + ((u>>16)&1u);
    return (unsigned short)(u>>16);
}
__device__ __forceinline__ float bf2f(unsigned short h){
    return __uint_as_float(((unsigned int)h)<<16);
}
__device__ __forceinline__ void gll16(const void* g, void* l){
    __builtin_amdgcn_global_load_lds((const __attribute__((address_space(1))) void*)g,
                                     (__attribute__((address_space(3))) void*)l, 16, 0, 0);
}
__device__ __forceinline__ void split_store(float v, ushort_t* ph, ushort_t* pl, int j){
    unsigned short h = f2bf(v);
    unsigned short l = f2bf(v - bf2f(h));
    ph[j] = h; pl[j] = l;
}

// ---------------- merged prepass (round-10 best) ----------------
__global__ void k_prep_all(
    const float* __restrict__ x, const float* __restrict__ h0, const float* __restrict__ c0,
    const float* __restrict__ W_ih, const float* __restrict__ W_hh,
    const float* __restrict__ b_ih, const float* __restrict__ b_hh,
    const float* __restrict__ W_sp, const float* __restrict__ W_sc, const float* __restrict__ W_tp,
    const float* __restrict__ b_sp, const float* __restrict__ b_sc, const float* __restrict__ b_tp,
    ushort_t* __restrict__ A1h, ushort_t* __restrict__ A1l,
    ushort_t* __restrict__ A2h, ushort_t* __restrict__ A2l,
    ushort_t* __restrict__ B1h, ushort_t* __restrict__ B1l,
    ushort_t* __restrict__ B2h, ushort_t* __restrict__ B2l,
    float* __restrict__ bgp, float* __restrict__ bs2)
{
    int bid = blockIdx.x;
    if (bid < 8192) {
        int u = bid*256 + threadIdx.x;
        int r  = u & 255;
        int c  = (u >> 8) & 3;
        int kt = (u >> 10) & 31;
        int tm = u >> 15;
        int row = tm*256 + r;
        int k0 = kt*32 + c*8;
        const float* src = (k0 < 512) ? (x + (size_t)row*512 + k0)
                                      : (h0 + (size_t)row*512 + (k0-512));
        float4 v0 = *(const float4*)(src);
        float4 v1 = *(const float4*)(src+4);
        float vv[8] = {v0.x,v0.y,v0.z,v0.w,v1.x,v1.y,v1.z,v1.w};
        size_t off = (size_t)u * 8;
#pragma unroll
        for (int j=0;j<8;++j) split_store(vv[j], A1h+off, A1l+off, j);
    } else if (bid < 12288) {
        int u = (bid-8192)*256 + threadIdx.x;
        int r  = u & 127;
        int c  = (u >> 7) & 3;
        int tk = (u >> 9) & 15;
        int tm = u >> 13;
        int row = tm*128 + r;
        int k0 = tk*32 + c*8;
        const float* src = c0 + (size_t)row*512 + k0;
        float4 v0 = *(const float4*)(src);
        float4 v1 = *(const float4*)(src+4);
        float vv[8] = {v0.x,v0.y,v0.z,v0.w,v1.x,v1.y,v1.z,v1.w};
        size_t off = ((size_t)tm*32 + tk)*4096 + (size_t)(c*128 + r)*8;
#pragma unroll
        for (int j=0;j<8;++j) split_store(vv[j], A2h+off, A2l+off, j);
    } else if (bid < 13312) {
        int u = (bid-12288)*256 + threadIdx.x;
        int r  = u & 255;
        int c  = (u >> 8) & 3;
        int kt = (u >> 10) & 31;
        int tn = u >> 15;
        int g = (r>>4)&3;
        int h = tn*64 + (r>>6)*16 + (r&15);
        int wrow = g*512 + h;
        int k0 = kt*32 + c*8;
        const float* src = (k0 < 512) ? (W_ih + (size_t)wrow*512 + k0)
                                      : (W_hh + (size_t)wrow*512 + (k0-512));
        float4 v0 = *(const float4*)(src);
        float4 v1 = *(const float4*)(src+4);
        float vv[8] = {v0.x,v0.y,v0.z,v0.w,v1.x,v1.y,v1.z,v1.w};
        size_t off = (size_t)u * 8;
#pragma unroll
        for (int j=0;j<8;++j) split_store(vv[j], B1h+off, B1l+off, j);
        if (kt == 0 && c == 0) bgp[tn*256 + r] = b_ih[wrow] + b_hh[wrow];
    } else {
        int u = (bid-13312)*256 + threadIdx.x;
        int r  = u & 127;
        int c  = (u >> 7) & 3;
        int tk = (u >> 9) & 31;
        int tn = u >> 14;
        int n = tn*128 + r;
        int k0 = tk*32 + c*8;
        float vv[8];
        if (n < 256) {
            const float* src = (k0 < 512) ? (W_sp + (size_t)n*512 + k0)
                                          : (W_sc + (size_t)n*512 + (k0-512));
            float4 v0 = *(const float4*)(src);
            float4 v1 = *(const float4*)(src+4);
            vv[0]=v0.x; vv[1]=v0.y; vv[2]=v0.z; vv[3]=v0.w;
            vv[4]=v1.x; vv[5]=v1.y; vv[6]=v1.z; vv[7]=v1.w;
        } else if (k0 < 512) {
            const float* src = W_tp + (size_t)(n-256)*512 + k0;
            float4 v0 = *(const float4*)(src);
            float4 v1 = *(const float4*)(src+4);
            vv[0]=v0.x; vv[1]=v0.y; vv[2]=v0.z; vv[3]=v0.w;
            vv[4]=v1.x; vv[5]=v1.y; vv[6]=v1.z; vv[7]=v1.w;
        } else {
#pragma unroll
            for (int j=0;j<8;++j) vv[j] = 0.0f;
        }
        size_t off = (size_t)u * 8;
#pragma unroll
        for (int j=0;j<8;++j) split_store(vv[j], B2h+off, B2l+off, j);
        if (tk == 0 && c == 0) bs2[n] = (n < 256) ? (b_sp[n] + b_sc[n]) : b_tp[n-256];
    }
}

// ---------- GEMM1: gates, 256x256, K''=3072, ping-pong, no scheduling pins ----------
#define GSTEP(T, CA, CB, NA, NB, DO_READS, DO_STAGE, VMASM)                          \
  {                                                                                  \
    if (DO_READS) {                                                                  \
        const ushort_t* bufA1 = &lds[((T)+1) & 3][0];                                \
        const ushort_t* bufB1 = &lds[((T)+1) & 3][8192];                             \
        _Pragma("unroll") for (int f = 0; f < 8; ++f)                                \
            NA[f] = *(const short8*)&bufA1[aoff[f]];                                 \
        _Pragma("unroll") for (int f = 0; f < 4; ++f)                                \
            NB[f] = *(const short8*)&bufB1[boff[f]];                                 \
    }                                                                                \
    if (DO_STAGE) {                                                                  \
        const int uu = (T) + 3;                                                      \
        const ushort_t* As_ = ((uu >> 5) == 1) ? Al : Ah;                            \
        const ushort_t* Bs_ = ((uu >> 5) == 2) ? Bl : Bh;                            \
        size_t ga = ((size_t)tm*32 + (uu & 31))*8192 + (size_t)tid*8;                \
        size_t gb = ((size_t)tn*32 + (uu & 31))*8192 + (size_t)tid*8;                \
        ushort_t* dA = &lds[uu & 3][0];                                              \
        ushort_t* dB = &lds[uu & 3][8192];                                           \
        gll16(As_ + ga,        dA + tid*8);                                          \
        gll16(As_ + ga + 4096, dA + 4096 + tid*8);                                   \
        gll16(Bs_ + gb,        dB + tid*8);                                          \
        gll16(Bs_ + gb + 4096, dB + 4096 + tid*8);                                   \
    }                                                                                \
    _Pragma("unroll") for (int fm = 0; fm < 8; ++fm)                                 \
        _Pragma("unroll") for (int fn = 0; fn < 4; ++fn)                             \
            acc[fm][fn] = __builtin_amdgcn_mfma_f32_16x16x32_bf16(CA[fm], CB[fn], acc[fm][fn], 0,0,0); \
    VMASM;                                                                           \
    asm volatile("s_barrier" ::: "memory");                                          \
  }

__global__ __launch_bounds__(512, 2) void k_gemm_gates(
    const ushort_t* __restrict__ Ah, const ushort_t* __restrict__ Al,
    const ushort_t* __restrict__ Bh, const ushort_t* __restrict__ Bl,
    const float* __restrict__ bgp, const float* __restrict__ c0,
    float* __restrict__ outH, float* __restrict__ outC,
    ushort_t* __restrict__ A2h, ushort_t* __restrict__ A2l)
{
    __shared__ __align__(16) ushort_t lds[4][16384];   // 128 KiB
    const int tid  = threadIdx.x;
    const int lane = tid & 63;
    const int wid  = tid >> 6;
    const int wr   = wid >> 2;        // 0..1
    const int wc   = wid & 3;         // 0..3
    const int l15  = lane & 15;
    const int lq   = lane >> 4;
    const int bid  = (int)blockIdx.x;
    const int v    = (bid & 7)*64 + (bid >> 3);   // XCD swizzle
    const int tm   = v >> 3;          // 0..63
    const int tn   = v & 7;           // 0..7

    f32x4 acc[8][4];
#pragma unroll
    for (int fn = 0; fn < 4; ++fn) {
        float bv = bgp[tn*256 + wc*64 + fn*16 + l15];
#pragma unroll
        for (int fm = 0; fm < 8; ++fm) {
            acc[fm][fn][0]=bv; acc[fm][fn][1]=bv; acc[fm][fn][2]=bv; acc[fm][fn][3]=bv;
        }
    }

    int aoff[8], boff[4];
#pragma unroll
    for (int f = 0; f < 8; ++f) aoff[f] = (lq*256 + wr*128 + f*16 + l15) * 8;
#pragma unroll
    for (int f = 0; f < 4; ++f) boff[f] = (lq*256 + wc*64 + f*16 + l15) * 8;

    short8 a0[8], b0[4], a1[8], b1[4];

    // prologue: stage steps 0,1,2; drain 0,1; preload frags of step 0 into set0
#pragma unroll
    for (int u0 = 0; u0 < 3; ++u0) {
        size_t ga = ((size_t)tm*32 + u0)*8192 + (size_t)tid*8;
        size_t gb = ((size_t)tn*32 + u0)*8192 + (size_t)tid*8;
        gll16(Ah + ga,        &lds[u0][0]     + tid*8);
        gll16(Ah + ga + 4096, &lds[u0][4096]  + tid*8);
        gll16(Bh + gb,        &lds[u0][8192]  + tid*8);
        gll16(Bh + gb + 4096, &lds[u0][12288] + tid*8);
    }
    asm volatile("s_waitcnt vmcnt(4)" ::: "memory");
    asm volatile("s_barrier" ::: "memory");
#pragma unroll
    for (int f = 0; f < 8; ++f) a0[f] = *(const short8*)&lds[0][aoff[f]];
#pragma unroll
    for (int f = 0; f < 4; ++f) b0[f] = *(const short8*)&lds[0][8192 + boff[f]];

    for (int t = 0; t < 92; t += 2) {
        GSTEP(t,   a0, b0, a1, b1, 1, 1, asm volatile("s_waitcnt vmcnt(4)" ::: "memory"));
        GSTEP(t+1, a1, b1, a0, b0, 1, 1, asm volatile("s_waitcnt vmcnt(4)" ::: "memory"));
    }
    GSTEP(92, a0, b0, a1, b1, 1, 1, asm volatile("s_waitcnt vmcnt(4)" ::: "memory"));
    GSTEP(93, a1, b1, a0, b0, 1, 0, asm volatile("s_waitcnt vmcnt(0)" ::: "memory"));
    GSTEP(94, a0, b0, a1, b1, 1, 0, ((void)0));
    GSTEP(95, a1, b1, a0, b0, 0, 0, ((void)0));

    // epilogue: lane holds 4 gates (fn) for rows lq*4+r, col h
    const int h = tn*64 + wc*16 + l15;
#pragma unroll
    for (int fm = 0; fm < 8; ++fm) {
        int row0 = tm*256 + wr*128 + fm*16 + lq*4;
#pragma unroll
        for (int r = 0; r < 4; ++r) {
            int row = row0 + r;
            size_t idx = (size_t)row*512 + h;
            float ig = sigm(acc[fm][0][r]);
            float fg = sigm(acc[fm][1][r]);
            float gg = tanhf(acc[fm][2][r]);
            float og = sigm(acc[fm][3][r]);
            float c1 = fg*c0[idx] + ig*gg;
            float h1 = og*tanhf(c1);
            outC[idx] = c1;
            outH[idx] = h1;
            unsigned short ch = f2bf(c1);
            unsigned short cl = f2bf(c1 - bf2f(ch));
            size_t a2 = ((size_t)(row>>7)*32 + 16 + (h>>5))*4096
                      + (size_t)((((h>>3)&3))*128 + (row&127))*8 + (h&7);
            A2h[a2] = ch;
            A2l[a2] = cl;
        }
    }
}

// ---------- GEMM2: sg|tg, 128x128, K''=3072, ping-pong, no scheduling pins ----------
#define SSTEP(T, CA, CB, NA, NB, DO_READS, DO_STAGE, VMASM)                          \
  {                                                                                  \
    if (DO_READS) {                                                                  \
        const ushort_t* bufA1 = &lds2[((T)+1) & 3][0];                               \
        const ushort_t* bufB1 = &lds2[((T)+1) & 3][4096];                            \
        _Pragma("unroll") for (int f = 0; f < 4; ++f)                                \
            NA[f] = *(const short8*)&bufA1[aoff[f]];                                 \
        _Pragma("unroll") for (int f = 0; f < 4; ++f)                                \
            NB[f] = *(const short8*)&bufB1[boff[f]];                                 \
    }                                                                                \
    if (DO_STAGE) {                                                                  \
        const int uu = (T) + 3;                                                      \
        const ushort_t* As_ = ((uu >> 5) == 1) ? Al : Ah;                            \
        const ushort_t* Bs_ = ((uu >> 5) == 2) ? Bl : Bh;                            \
        size_t ga = ((size_t)tm*32 + (uu & 31))*4096 + (size_t)tid*8;                \
        size_t gb = ((size_t)tn*32 + (uu & 31))*4096 + (size_t)tid*8;                \
        ushort_t* dA = &lds2[uu & 3][0];                                             \
        ushort_t* dB = &lds2[uu & 3][4096];                                          \
        gll16(As_ + ga,        dA + tid*8);                                          \
        gll16(As_ + ga + 2048, dA + 2048 + tid*8);                                   \
        gll16(Bs_ + gb,        dB + tid*8);                                          \
        gll16(Bs_ + gb + 2048, dB + 2048 + tid*8);                                   \
    }                                                                                \
    _Pragma("unroll") for (int fm = 0; fm < 4; ++fm)                                 \
        _Pragma("unroll") for (int fn = 0; fn < 4; ++fn)                             \
            acc[fm][fn] = __builtin_amdgcn_mfma_f32_16x16x32_bf16(CA[fm], CB[fn], acc[fm][fn], 0,0,0); \
    VMASM;                                                                           \
    asm volatile("s_barrier" ::: "memory");                                          \
  }

__global__ __launch_bounds__(256, 2) void k_gemm_sgtg(
    const ushort_t* __restrict__ Ah, const ushort_t* __restrict__ Al,
    const ushort_t* __restrict__ Bh, const ushort_t* __restrict__ Bl,
    const float* __restrict__ bs2,
    float* __restrict__ sgtg)
{
    __shared__ __align__(16) ushort_t lds2[4][8192];   // 64 KiB -> 2 blocks/CU
    const int tid  = threadIdx.x;
    const int lane = tid & 63;
    const int wid  = tid >> 6;
    const int wr   = wid >> 1;
    const int wc   = wid & 1;
    const int l15  = lane & 15;
    const int lq   = lane >> 4;
    const int bid  = (int)blockIdx.x;
    const int v    = (bid & 7)*64 + (bid >> 3);
    const int tm   = v >> 2;          // 0..127
    const int tn   = v & 3;           // 0..3

    f32x4 acc[4][4];
#pragma unroll
    for (int fn = 0; fn < 4; ++fn) {
        float bv = bs2[tn*128 + wc*64 + fn*16 + l15];
#pragma unroll
        for (int fm = 0; fm < 4; ++fm) {
            acc[fm][fn][0]=bv; acc[fm][fn][1]=bv; acc[fm][fn][2]=bv; acc[fm][fn][3]=bv;
        }
    }

    int aoff[4], boff[4];
#pragma unroll
    for (int f = 0; f < 4; ++f) {
        aoff[f] = (lq*128 + wr*64 + f*16 + l15) * 8;
        boff[f] = (lq*128 + wc*64 + f*16 + l15) * 8;
    }

    short8 a0[4], b0[4], a1[4], b1[4];

#pragma unroll
    for (int u0 = 0; u0 < 3; ++u0) {
        size_t ga = ((size_t)tm*32 + u0)*4096 + (size_t)tid*8;
        size_t gb = ((size_t)tn*32 + u0)*4096 + (size_t)tid*8;
        gll16(Ah + ga,        &lds2[u0][0]    + tid*8);
        gll16(Ah + ga + 2048, &lds2[u0][2048] + tid*8);
        gll16(Bh + gb,        &lds2[u0][4096] + tid*8);
        gll16(Bh + gb + 2048, &lds2[u0][6144] + tid*8);
    }
    asm volatile("s_waitcnt vmcnt(4)" ::: "memory");
    asm volatile("s_barrier" ::: "memory");
#pragma unroll
    for (int f = 0; f < 4; ++f) a0[f] = *(const short8*)&lds2[0][aoff[f]];
#pragma unroll
    for (int f = 0; f < 4; ++f) b0[f] = *(const short8*)&lds2[0][4096 + boff[f]];

    for (int t = 0; t < 92; t += 2) {
        SSTEP(t,   a0, b0, a1, b1, 1, 1, asm volatile("s_waitcnt vmcnt(4)" ::: "memory"));
        SSTEP(t+1, a1, b1, a0, b0, 1, 1, asm volatile("s_waitcnt vmcnt(4)" ::: "memory"));
    }
    SSTEP(92, a0, b0, a1, b1, 1, 1, asm volatile("s_waitcnt vmcnt(4)" ::: "memory"));
    SSTEP(93, a1, b1, a0, b0, 1, 0, asm volatile("s_waitcnt vmcnt(0)" ::: "memory"));
    SSTEP(94, a0, b0, a1, b1, 1, 0, ((void)0));
    SSTEP(95, a1, b1, a0, b0, 0, 0, ((void)0));

#pragma unroll
    for (int fm = 0; fm < 4; ++fm) {
        int row0 = tm*128 + wr*64 + fm*16 + lq*4;
#pragma unroll
        for (int fn = 0; fn < 4; ++fn) {
            int n = tn*128 + wc*64 + fn*16 + l15;
#pragma unroll
            for (int r = 0; r < 4; ++r) {
                int row = row0 + r;
                float vv = acc[fm][fn][r];
                vv = vv > 0.f ? vv : 0.01f*vv;
                sgtg[(size_t)row*512 + n] = vv;
            }
        }
    }
}

// ---------- final: row dots, threshold decision, gated writeback ----------
__global__ __launch_bounds__(256) void k_final(
    const float* __restrict__ sgtg,
    const float* __restrict__ h0, const float* __restrict__ c0,
    const float* __restrict__ cum,
    const float* __restrict__ W_so, const float* __restrict__ b_so,
    const float* __restrict__ W_to, const float* __restrict__ b_to,
    float* __restrict__ outH, float* __restrict__ outC,
    float* __restrict__ outCum, float* __restrict__ outDelta, float* __restrict__ outProb)
{
    int w = threadIdx.x >> 6;
    int lane = threadIdx.x & 63;
    int b = blockIdx.x * 4 + w;
    const float* row = sgtg + (size_t)b * 512;
    float so = 0.f, to = 0.f;
#pragma unroll
    for (int u = 0; u < 4; ++u) {
        int c = lane + 64 * u;
        so = fmaf(row[c], W_so[c], so);
        to = fmaf(row[256 + c], W_to[c], to);
    }
#pragma unroll
    for (int off = 32; off; off >>= 1) {
        so += __shfl_down(so, off);
        to += __shfl_down(to, off);
    }
    so = __shfl(so, 0);
    to = __shfl(to, 0);
    float delta = sigm(so + b_so[0]);
    float thr   = sigm(to + b_to[0]);
    float cu = cum[b];
    float prob = cu + fminf(delta, 1.0f - cu);
    float hard = (prob > thr) ? 1.0f : 0.0f;
    if (lane == 0) {
        outDelta[b] = delta;
        outProb[b]  = prob;
        outCum[b]   = (1.0f - hard) * prob;
    }
    if (hard == 0.0f) {
#pragma unroll
        for (int u = 0; u < 8; ++u) {
            size_t idx = (size_t)b * 512 + lane + 64 * u;
            outH[idx] = h0[idx];
            outC[idx] = c0[idx];
        }
    }
}

extern "C" void kernel_launch(void* const* d_in, const int* in_sizes, int n_in,
                              void* d_out, int out_size, void* d_ws, size_t ws_size,
                              hipStream_t stream)
{
    const float* x    = (const float*)d_in[0];
    const float* h0   = (const float*)d_in[1];
    const float* c0   = (const float*)d_in[2];
    const float* cum  = (const float*)d_in[3];
    const float* W_ih = (const float*)d_in[4];
    const float* W_hh = (const float*)d_in[5];
    const float* b_ih = (const float*)d_in[6];
    const float* b_hh = (const float*)d_in[7];
    const float* W_sp = (const float*)d_in[8];
    const float* b_sp = (const float*)d_in[9];
    const float* W_sc = (const float*)d_in[10];
    const float* b_sc = (const float*)d_in[11];
    const float* W_so = (const float*)d_in[12];
    const float* b_so = (const float*)d_in[13];
    const float* W_tp = (const float*)d_in[14];
    const float* b_tp = (const float*)d_in[15];
    const float* W_to = (const float*)d_in[16];
    const float* b_to = (const float*)d_in[17];

    float* out      = (float*)d_out;
    float* outH     = out;
    float* outC     = out + (size_t)BB * HH;
    float* outCum   = out + (size_t)2 * BB * HH;
    float* outDelta = outCum + BB;
    float* outProb  = outDelta + BB;

    char* w = (char*)d_ws;
    ushort_t* A1h = (ushort_t*)(w);                       // 33,554,432 B
    ushort_t* A1l = (ushort_t*)(w + 33554432ull);         // 33,554,432 B
    ushort_t* A2h = (ushort_t*)(w + 67108864ull);         // 33,554,432 B
    ushort_t* A2l = (ushort_t*)(w + 100663296ull);        // 33,554,432 B
    ushort_t* B1h = (ushort_t*)(w + 134217728ull);        //  4,194,304 B
    ushort_t* B1l = (ushort_t*)(w + 138412032ull);        //  4,194,304 B
    ushort_t* B2h = (ushort_t*)(w + 142606336ull);        //  1,048,576 B
    ushort_t* B2l = (ushort_t*)(w + 143654912ull);        //  1,048,576 B
    float*    bgp = (float*)(w + 144703488ull);           //      8,192 B
    float*    bs2 = (float*)(w + 144711680ull);           //      2,048 B
    float*    sgtg = (float*)A1h;   // alias: A1 dead after k_gemm_gates

    k_prep_all<<<13568, 256, 0, stream>>>(x, h0, c0, W_ih, W_hh, b_ih, b_hh,
                                          W_sp, W_sc, W_tp, b_sp, b_sc, b_tp,
                                          A1h, A1l, A2h, A2l, B1h, B1l, B2h, B2l,
                                          bgp, bs2);
    k_gemm_gates<<<512, 512, 0, stream>>>(A1h, A1l, B1h, B1l, bgp, c0,
                                          outH, outC, A2h, A2l);
    k_gemm_sgtg<<<512, 256, 0, stream>>>(A2h, A2l, B2h, B2l, bs2, sgtg);
    k_final<<<4096, 256, 0, stream>>>(sgtg, h0, c0, cum, W_so, b_so, W_to, b_to,
                                      outH, outC, outCum, outDelta, outProb);
}